// Round 3
// baseline (515.430 us; speedup 1.0000x reference)
//
#include <hip/hip_runtime.h>
#include <stdint.h>

#define GN 2048
#define EN 512
#define BN 16

__device__ __forceinline__ float bf2f(unsigned short u) {
    return __uint_as_float(((unsigned int)u) << 16);
}
__device__ __forceinline__ unsigned short f2bf(float f) {
    unsigned int u = __float_as_uint(f);
    u += 0x7fffu + ((u >> 16) & 1u);   // RNE
    return (unsigned short)(u >> 16);
}
__device__ __forceinline__ float lrelu(float v) { return v > 0.f ? v : 0.01f * v; }

union U16x8 { uint4 v; unsigned short s[8]; };

template<bool ISBF>
__device__ __forceinline__ float ldf(const void* p, size_t i) {
    if (ISBF) return bf2f(((const unsigned short*)p)[i]);
    return ((const float*)p)[i];
}

template<bool ISBF>
__device__ __forceinline__ void ld8(const void* p, size_t off, float* v) {
    if (ISBF) {
        U16x8 u; u.v = *(const uint4*)((const unsigned short*)p + off);
        #pragma unroll
        for (int i = 0; i < 8; i++) v[i] = bf2f(u.s[i]);
    } else {
        const float* q = (const float*)p + off;
        const float4 a = *(const float4*)q;
        const float4 b = *(const float4*)(q + 4);
        v[0]=a.x; v[1]=a.y; v[2]=a.z; v[3]=a.w;
        v[4]=b.x; v[5]=b.y; v[6]=b.z; v[7]=b.w;
    }
}

// ---------------------------------------------------------------------------
// SNIFF: bf16 vs fp32 runtime detection on embMat (~N(0,1)).
// ---------------------------------------------------------------------------
__global__ void sniff_k(const unsigned int* __restrict__ emb, int* __restrict__ flag) {
    const int t = threadIdx.x;
    const unsigned int w = emb[t];
    const int e = (w >> 7) & 0xFF;
    const int ok = (e >= 108 && e <= 134) ? 1 : 0;
    const unsigned long long m = __ballot(ok);
    if (t == 0) flag[0] = (__popcll(m) >= 40) ? 1 : 0;
}

// ---------------------------------------------------------------------------
// SETUP (grid 400):
//  blocks [0,16):    xpackT[t][b] bytes: bit i = (datax[b, 8t+i] != 0)
//  blocks [16,272):  qk — one wave per (W in {Wq,Wk}, f): dots vs emb rows 0,1
//  blocks [272,400): weff partials — block pb covers rows [16pb,16pb+16)
// ---------------------------------------------------------------------------
template<bool ISBF>
__device__ __forceinline__ void setup_body(
    const int* __restrict__ datax, const void* emb, const void* Wq, const void* Wk,
    const void* fc1w, const void* fcCox,
    unsigned char* __restrict__ xpackT, float* __restrict__ qk,
    float* __restrict__ partials)
{
    const int blk = blockIdx.x;
    const int t = threadIdx.x;

    if (blk < 16) {
        const int b = blk;
        unsigned int byte = 0;
        const int base = b * GN + t * 8;
        #pragma unroll
        for (int i = 0; i < 8; i++)
            byte |= (datax[base + i] != 0 ? 1u : 0u) << i;
        xpackT[t * 16 + b] = (unsigned char)byte;
    } else if (blk < 272) {
        const int iw = (blk - 16) * 4 + (t >> 6);   // 0..1023
        const int lane = t & 63;
        const void* W = (iw < 512) ? Wq : Wk;
        const int f = iw & 511;
        float w8[8], e0[8], e1[8];
        ld8<ISBF>(W, (size_t)f * EN + lane * 8, w8);
        ld8<ISBF>(emb, (size_t)lane * 8, e0);
        ld8<ISBF>(emb, (size_t)EN + lane * 8, e1);
        float d0 = 0.f, d1 = 0.f;
        #pragma unroll
        for (int i = 0; i < 8; i++) { d0 += w8[i] * e0[i]; d1 += w8[i] * e1[i]; }
        for (int o = 32; o >= 1; o >>= 1) {
            d0 += __shfl_xor(d0, o);
            d1 += __shfl_xor(d1, o);
        }
        if (lane == 0) {
            const int base = (iw < 512) ? 0 : 1024;
            qk[base + f] = d0;          // dot with emb row 0
            qk[base + 512 + f] = d1;    // dot with emb row 1
        }
    } else {
        const int pb = blk - 272;                    // 0..127
        float acc[8] = {0.f,0.f,0.f,0.f,0.f,0.f,0.f,0.f};
        for (int r = 0; r < 16; r++) {
            const int g = pb * 16 + r;
            const float c = ldf<ISBF>(fcCox, g);
            float w8[8];
            ld8<ISBF>(fc1w, (size_t)g * GN + t * 8, w8);
            #pragma unroll
            for (int i = 0; i < 8; i++) acc[i] += c * w8[i];
        }
        float* q = partials + (size_t)pb * GN + t * 8;
        *(float4*)q       = make_float4(acc[0], acc[1], acc[2], acc[3]);
        *(float4*)(q + 4) = make_float4(acc[4], acc[5], acc[6], acc[7]);
    }
}

__global__ __launch_bounds__(256) void setup_k(
    const int* datax, const void* emb, const void* Wq, const void* Wk,
    const void* fc1w, const void* fcCox,
    unsigned char* xpackT, float* qk, float* partials, const int* flag)
{
    if (flag[0]) setup_body<true>(datax, emb, Wq, Wk, fc1w, fcCox, xpackT, qk, partials);
    else         setup_body<false>(datax, emb, Wq, Wk, fc1w, fcCox, xpackT, qk, partials);
}

// ---------------------------------------------------------------------------
// PRE2 (grid 9): block 0: s00..s11 + bias-dot constant; blocks 1..8: weff reduce
// ---------------------------------------------------------------------------
template<bool ISBF>
__device__ __forceinline__ void pre2_body(
    const float* __restrict__ qk, const void* fc1b, const void* fcCox,
    const float* __restrict__ partials,
    float* __restrict__ sv, float* __restrict__ cptr, float* __restrict__ weff)
{
    const int t = threadIdx.x;
    if (blockIdx.x > 0) {
        const int c = (blockIdx.x - 1) * 256 + t;
        float acc = 0.f;
        for (int r = 0; r < 128; r++)
            acc += partials[(size_t)r * GN + c];
        weff[c] = acc;
        return;
    }
    float a[5] = {0.f, 0.f, 0.f, 0.f, 0.f};
    for (int e = t; e < EN; e += 256) {
        float q0 = qk[e], q1 = qk[EN + e];
        float K0 = qk[2 * EN + e], K1 = qk[3 * EN + e];
        a[0] += q0 * K0; a[1] += q0 * K1; a[2] += q1 * K0; a[3] += q1 * K1;
    }
    for (int gg = t; gg < GN; gg += 256)
        a[4] += ldf<ISBF>(fc1b, gg) * ldf<ISBF>(fcCox, gg);
    for (int o = 32; o >= 1; o >>= 1)
        #pragma unroll
        for (int j = 0; j < 5; j++) a[j] += __shfl_xor(a[j], o);
    __shared__ float red[4][5];
    int wid = t >> 6, lane = t & 63;
    if (lane == 0)
        for (int j = 0; j < 5; j++) red[wid][j] = a[j];
    __syncthreads();
    if (t == 0) {
        for (int j = 0; j < 4; j++)
            sv[j] = red[0][j] + red[1][j] + red[2][j] + red[3][j];
        cptr[0] = red[0][4] + red[1][4] + red[2][4] + red[3][4];
    }
}

__global__ __launch_bounds__(256) void pre2_k(
    const float* qk, const void* fc1b, const void* fcCox, const float* partials,
    float* sv, float* cptr, float* weff, const int* flag)
{
    if (flag[0]) pre2_body<true>(qk, fc1b, fcCox, partials, sv, cptr, weff);
    else         pre2_body<false>(qk, fc1b, fcCox, partials, sv, cptr, weff);
}

// ---------------------------------------------------------------------------
// PASS A (grid 2048): bias row compute + softmax sums + attn2; stores fp32
// bias row to workspace (issued early, drains under the shuffle reductions).
// ---------------------------------------------------------------------------
template<bool ISBF>
__device__ __forceinline__ void attnA_body(
    const void* k1, const void* k2, const void* k3,
    const void* sp, const void* cen, const void* pad,
    const unsigned char* __restrict__ xpackT, const float* __restrict__ sv,
    float* __restrict__ attn2, float* __restrict__ biasws)
{
    const int g = blockIdx.x;
    const int t = threadIdx.x;
    const int h0 = t << 3;
    const size_t roff = (size_t)g * GN + h0;

    const float lr3 = lrelu(ldf<ISBF>(k3, 0));

    float a1[8], a2[8], vsp[8], vcn[8], vpd[8];
    ld8<ISBF>(k1, roff, a1);
    ld8<ISBF>(k2, roff, a2);
    ld8<ISBF>(sp, roff, vsp);
    ld8<ISBF>(cen, roff, vcn);
    ld8<ISBF>(pad, roff, vpd);

    float bias8[8];
    float lmax = -3.4e38f;
    #pragma unroll
    for (int i = 0; i < 8; i++) {
        float b = lrelu(a1[i]) * vsp[i] + lrelu(a2[i]) * vcn[i] + lr3 * vpd[i];
        bias8[i] = b;
        lmax = fmaxf(lmax, b);
    }
    // store bias row early — drains while we do the reductions below
    float* bq = biasws + roff;
    *(float4*)bq       = make_float4(bias8[0], bias8[1], bias8[2], bias8[3]);
    *(float4*)(bq + 4) = make_float4(bias8[4], bias8[5], bias8[6], bias8[7]);

    for (int o = 32; o >= 1; o >>= 1) lmax = fmaxf(lmax, __shfl_xor(lmax, o));

    __shared__ float smax[4];
    __shared__ float redT[4];
    __shared__ float red[4][BN];
    const int wid = t >> 6, lane = t & 63;
    if (lane == 0) smax[wid] = lmax;
    __syncthreads();
    const float Mg = fmaxf(fmaxf(smax[0], smax[1]), fmaxf(smax[2], smax[3]));

    float E8[8];
    float Tl = 0.f;
    #pragma unroll
    for (int i = 0; i < 8; i++) { E8[i] = __expf(bias8[i] - Mg); Tl += E8[i]; }

    const uint4 pk = *(const uint4*)(xpackT + (size_t)t * 16);
    const unsigned char* pb = (const unsigned char*)&pk;

    float s1l[BN];
    #pragma unroll
    for (int b = 0; b < BN; b++) {
        const unsigned int mk = pb[b];
        float acc1 = 0.f;
        #pragma unroll
        for (int i = 0; i < 8; i++)
            acc1 += ((mk >> i) & 1u) ? E8[i] : 0.f;
        s1l[b] = acc1;
    }
    for (int o = 32; o >= 1; o >>= 1) {
        Tl += __shfl_xor(Tl, o);
        #pragma unroll
        for (int b = 0; b < BN; b++) s1l[b] += __shfl_xor(s1l[b], o);
    }
    if (lane == 0) {
        redT[wid] = Tl;
        #pragma unroll
        for (int b = 0; b < BN; b++) red[wid][b] = s1l[b];
    }
    __syncthreads();

    if (t < BN) {
        const int b = t;
        const float s00 = sv[0], s01 = sv[1], s10 = sv[2], s11 = sv[3];
        const uint4 gk = *(const uint4*)(xpackT + (size_t)(g >> 3) * 16);
        const unsigned char* gb = (const unsigned char*)&gk;
        const int gbit = g & 7;
        const float Tg = redT[0] + redT[1] + redT[2] + redT[3];
        const float S1 = fmaxf(red[0][b] + red[1][b] + red[2][b] + red[3][b], 1e-30f);
        const float S0 = fmaxf(Tg - S1, 1e-30f);
        const bool on = ((gb[b] >> gbit) & 1u) != 0u;
        const float sa0 = on ? s10 : s00;
        const float sa1 = on ? s11 : s01;
        const float d = (sa0 + __logf(S0)) - (sa1 + __logf(S1));
        const float attnv = 1.f / (1.f + __expf(d));
        attn2[b * GN + g] = (on ? 1.f : 0.f) + attnv;
    }
}

__global__ __launch_bounds__(256) void attnA_k(
    const void* k1, const void* k2, const void* k3,
    const void* sp, const void* cen, const void* pad,
    const unsigned char* xpackT, const float* sv, float* attn2,
    float* biasws, const int* flag)
{
    if (flag[0]) attnA_body<true>(k1, k2, k3, sp, cen, pad, xpackT, sv, attn2, biasws);
    else         attnA_body<false>(k1, k2, k3, sp, cen, pad, xpackT, sv, attn2, biasws);
}

// ---------------------------------------------------------------------------
// PASS B (grid 2048): block = (batch b = id&15, chunk of 16 g-rows = id>>4).
// Reads fp32 bias rows (L3-shared across the 16 b's of the same chunk),
// adds s[on(b,g)][bit(b,h)], writes 64 KB CONTIGUOUS per block into one
// batch plane with plain cached stores (full-line L2 writebacks).
// ---------------------------------------------------------------------------
template<bool ISBF>
__device__ __forceinline__ void attnB_body(
    const float* __restrict__ biasws, const unsigned char* __restrict__ xpackT,
    const float* __restrict__ sv, void* d_out)
{
    const int id = blockIdx.x;
    const int b  = id & 15;
    const int ch = id >> 4;            // 0..127
    const int t  = threadIdx.x;
    const int h0 = t << 3;

    const float s00 = sv[0], s01 = sv[1], s10 = sv[2], s11 = sv[3];
    const unsigned int mk = xpackT[t * 16 + b];

    #pragma unroll 2
    for (int r = 0; r < 16; r++) {
        const int g = ch * 16 + r;
        const unsigned int gbyte = xpackT[(g >> 3) * 16 + b];
        const bool on = ((gbyte >> (g & 7)) & 1u) != 0u;
        const float c0 = on ? s10 : s00;
        const float c1 = on ? s11 : s01;

        const float* br = biasws + (size_t)g * GN + h0;
        const float4 x0 = *(const float4*)br;
        const float4 x1 = *(const float4*)(br + 4);
        float v[8] = {x0.x, x0.y, x0.z, x0.w, x1.x, x1.y, x1.z, x1.w};
        float ov[8];
        #pragma unroll
        for (int i = 0; i < 8; i++)
            ov[i] = v[i] + (((mk >> i) & 1u) ? c1 : c0);

        const size_t ooff = (size_t)b * GN * GN + (size_t)g * GN + h0;
        if (ISBF) {
            U16x8 u;
            #pragma unroll
            for (int i = 0; i < 8; i++) u.s[i] = f2bf(ov[i]);
            *(uint4*)((unsigned short*)d_out + BN + ooff) = u.v;
        } else {
            float* q = (float*)d_out + BN + ooff;
            *(float4*)q       = make_float4(ov[0], ov[1], ov[2], ov[3]);
            *(float4*)(q + 4) = make_float4(ov[4], ov[5], ov[6], ov[7]);
        }
    }
}

__global__ __launch_bounds__(256) void attnB_k(
    const float* biasws, const unsigned char* xpackT, const float* sv,
    void* d_out, const int* flag)
{
    if (flag[0]) attnB_body<true>(biasws, xpackT, sv, d_out);
    else         attnB_body<false>(biasws, xpackT, sv, d_out);
}

// ---------------------------------------------------------------------------
// FALLBACK single-pass (used only if workspace too small): round-2 kernel
// with PLAIN stores (no nontemporal).
// ---------------------------------------------------------------------------
template<bool ISBF>
__device__ __forceinline__ void attn_body(
    const void* k1, const void* k2, const void* k3,
    const void* sp, const void* cen, const void* pad,
    const unsigned char* __restrict__ xpackT, const float* __restrict__ sv,
    float* __restrict__ attn2, void* d_out)
{
    const int g = blockIdx.x;
    const int t = threadIdx.x;
    const int h0 = t << 3;
    const size_t roff = (size_t)g * GN + h0;

    const float lr3 = lrelu(ldf<ISBF>(k3, 0));

    float a1[8], a2[8], vsp[8], vcn[8], vpd[8];
    ld8<ISBF>(k1, roff, a1);
    ld8<ISBF>(k2, roff, a2);
    ld8<ISBF>(sp, roff, vsp);
    ld8<ISBF>(cen, roff, vcn);
    ld8<ISBF>(pad, roff, vpd);

    float bias8[8];
    float lmax = -3.4e38f;
    #pragma unroll
    for (int i = 0; i < 8; i++) {
        float b = lrelu(a1[i]) * vsp[i] + lrelu(a2[i]) * vcn[i] + lr3 * vpd[i];
        bias8[i] = b;
        lmax = fmaxf(lmax, b);
    }
    for (int o = 32; o >= 1; o >>= 1) lmax = fmaxf(lmax, __shfl_xor(lmax, o));

    __shared__ float smax[4];
    __shared__ float redT[4];
    __shared__ float red[4][BN];
    const int wid = t >> 6, lane = t & 63;
    if (lane == 0) smax[wid] = lmax;
    __syncthreads();
    const float Mg = fmaxf(fmaxf(smax[0], smax[1]), fmaxf(smax[2], smax[3]));

    float E8[8];
    float Tl = 0.f;
    #pragma unroll
    for (int i = 0; i < 8; i++) { E8[i] = __expf(bias8[i] - Mg); Tl += E8[i]; }

    const uint4 pk = *(const uint4*)(xpackT + (size_t)t * 16);
    const unsigned char* pb = (const unsigned char*)&pk;

    float s1l[BN];
    #pragma unroll
    for (int b = 0; b < BN; b++) {
        const unsigned int mk = pb[b];
        float acc1 = 0.f;
        #pragma unroll
        for (int i = 0; i < 8; i++)
            acc1 += ((mk >> i) & 1u) ? E8[i] : 0.f;
        s1l[b] = acc1;
    }
    for (int o = 32; o >= 1; o >>= 1) {
        Tl += __shfl_xor(Tl, o);
        #pragma unroll
        for (int b = 0; b < BN; b++) s1l[b] += __shfl_xor(s1l[b], o);
    }
    if (lane == 0) {
        redT[wid] = Tl;
        #pragma unroll
        for (int b = 0; b < BN; b++) red[wid][b] = s1l[b];
    }
    __syncthreads();

    const float s00 = sv[0], s01 = sv[1], s10 = sv[2], s11 = sv[3];
    const uint4 gk = *(const uint4*)(xpackT + (size_t)(g >> 3) * 16);
    const unsigned char* gb = (const unsigned char*)&gk;
    const int gbit = g & 7;

    if (t < BN) {
        const int b = t;
        const float Tg = redT[0] + redT[1] + redT[2] + redT[3];
        const float S1 = fmaxf(red[0][b] + red[1][b] + red[2][b] + red[3][b], 1e-30f);
        const float S0 = fmaxf(Tg - S1, 1e-30f);
        const bool on = ((gb[b] >> gbit) & 1u) != 0u;
        const float sa0 = on ? s10 : s00;
        const float sa1 = on ? s11 : s01;
        const float d = (sa0 + __logf(S0)) - (sa1 + __logf(S1));
        const float attnv = 1.f / (1.f + __expf(d));
        attn2[b * GN + g] = (on ? 1.f : 0.f) + attnv;
    }

    if (ISBF) {
        U16x8 p00, p01, p10, p11;
        #pragma unroll
        for (int i = 0; i < 8; i++) {
            p00.s[i] = f2bf(bias8[i] + s00);
            p01.s[i] = f2bf(bias8[i] + s01);
            p10.s[i] = f2bf(bias8[i] + s10);
            p11.s[i] = f2bf(bias8[i] + s11);
        }
        unsigned short* outp = (unsigned short*)d_out + BN + (size_t)g * GN + h0;
        #pragma unroll
        for (int b = 0; b < BN; b++) {
            const unsigned int mk = pb[b];
            const bool on = ((gb[b] >> gbit) & 1u) != 0u;
            U16x8 lo, hi;
            if (on) { lo = p10; hi = p11; } else { lo = p00; hi = p01; }
            U16x8 o;
            #pragma unroll
            for (int i = 0; i < 8; i++)
                o.s[i] = ((mk >> i) & 1u) ? hi.s[i] : lo.s[i];
            *(uint4*)(outp + (size_t)b * GN * GN) = o.v;
        }
    } else {
        float v00[8], v01[8], v10[8], v11[8];
        #pragma unroll
        for (int i = 0; i < 8; i++) {
            v00[i] = bias8[i] + s00;
            v01[i] = bias8[i] + s01;
            v10[i] = bias8[i] + s10;
            v11[i] = bias8[i] + s11;
        }
        float* outp = (float*)d_out + BN + (size_t)g * GN + h0;
        #pragma unroll
        for (int b = 0; b < BN; b++) {
            const unsigned int mk = pb[b];
            const bool on = ((gb[b] >> gbit) & 1u) != 0u;
            float ov[8];
            #pragma unroll
            for (int i = 0; i < 8; i++) {
                const float lo = on ? v10[i] : v00[i];
                const float hi = on ? v11[i] : v01[i];
                ov[i] = ((mk >> i) & 1u) ? hi : lo;
            }
            float* q = outp + (size_t)b * GN * GN;
            *(float4*)q       = make_float4(ov[0], ov[1], ov[2], ov[3]);
            *(float4*)(q + 4) = make_float4(ov[4], ov[5], ov[6], ov[7]);
        }
    }
}

__global__ __launch_bounds__(256) void attn_k(
    const void* k1, const void* k2, const void* k3,
    const void* sp, const void* cen, const void* pad,
    const unsigned char* xpackT, const float* sv, float* attn2,
    void* d_out, const int* flag)
{
    if (flag[0]) attn_body<true>(k1, k2, k3, sp, cen, pad, xpackT, sv, attn2, d_out);
    else         attn_body<false>(k1, k2, k3, sp, cen, pad, xpackT, sv, attn2, d_out);
}

// ---------------------------------------------------------------------------
// FIN: out[b] = c + sum_g attn2[b,g] * w_eff[g]
// ---------------------------------------------------------------------------
template<bool ISBF>
__device__ __forceinline__ void final_body(
    const float* __restrict__ attn2, const float* __restrict__ weff,
    const float* __restrict__ cptr, void* d_out)
{
    const int b = blockIdx.x, t = threadIdx.x;
    const int h0 = t << 3;
    const float4 a0 = *(const float4*)(attn2 + b * GN + h0);
    const float4 a1 = *(const float4*)(attn2 + b * GN + h0 + 4);
    const float4 w0 = *(const float4*)(weff + h0);
    const float4 w1 = *(const float4*)(weff + h0 + 4);
    float acc = a0.x * w0.x + a0.y * w0.y + a0.z * w0.z + a0.w * w0.w
              + a1.x * w1.x + a1.y * w1.y + a1.z * w1.z + a1.w * w1.w;
    for (int o = 32; o >= 1; o >>= 1) acc += __shfl_xor(acc, o);
    __shared__ float red[4];
    const int wid = t >> 6, lane = t & 63;
    if (lane == 0) red[wid] = acc;
    __syncthreads();
    if (t == 0) {
        const float val = cptr[0] + red[0] + red[1] + red[2] + red[3];
        if (ISBF) ((unsigned short*)d_out)[b] = f2bf(val);
        else      ((float*)d_out)[b] = val;
    }
}

__global__ __launch_bounds__(256) void final_k(
    const float* attn2, const float* weff, const float* cptr,
    void* d_out, const int* flag)
{
    if (flag[0]) final_body<true>(attn2, weff, cptr, d_out);
    else         final_body<false>(attn2, weff, cptr, d_out);
}

extern "C" void kernel_launch(void* const* d_in, const int* in_sizes, int n_in,
                              void* d_out, int out_size, void* d_ws, size_t ws_size,
                              hipStream_t stream) {
    const int*  datax = (const int*)d_in[0];
    const void* emb   = d_in[1];
    const void* Wq    = d_in[2];
    const void* Wk    = d_in[3];
    const void* k1    = d_in[4];
    const void* k2    = d_in[5];
    const void* k3    = d_in[6];
    const void* sp    = d_in[7];
    const void* cen   = d_in[8];
    const void* pad   = d_in[9];
    const void* fc1w  = d_in[10];
    const void* fc1b  = d_in[11];
    const void* fcCox = d_in[12];

    float* ws       = (float*)d_ws;
    float* qk       = ws;                   // 2048 floats
    float* sv       = ws + 2048;            // 4
    float* cptr     = ws + 2052;            // 1
    float* weff     = ws + 2056;            // 2048
    float* attn2    = ws + 4104;            // 32768
    float* partials = ws + 36872;           // 128*2048 = 262144
    unsigned char* xpackT = (unsigned char*)(ws + 299016); // 4096 B
    int*   flag     = (int*)(ws + 300040);  // 1 int
    const size_t WS_BIAS_OFF = 302080;      // floats, 16B-aligned
    float* biasws   = ws + WS_BIAS_OFF;     // 2048*2048 fp32 = 16 MiB
    const size_t WS_NEED = (WS_BIAS_OFF + (size_t)GN * GN) * sizeof(float);

    sniff_k<<<1, 64, 0, stream>>>((const unsigned int*)emb, flag);
    setup_k<<<400, 256, 0, stream>>>(datax, emb, Wq, Wk, fc1w, fcCox,
                                     xpackT, qk, partials, flag);
    pre2_k<<<9, 256, 0, stream>>>(qk, fc1b, fcCox, partials, sv, cptr, weff, flag);
    if (ws_size >= WS_NEED) {
        attnA_k<<<GN, 256, 0, stream>>>(k1, k2, k3, sp, cen, pad, xpackT, sv,
                                        attn2, biasws, flag);
        attnB_k<<<GN, 256, 0, stream>>>(biasws, xpackT, sv, d_out, flag);
    } else {
        attn_k<<<GN, 256, 0, stream>>>(k1, k2, k3, sp, cen, pad, xpackT, sv,
                                       attn2, d_out, flag);
    }
    final_k<<<BN, 256, 0, stream>>>(attn2, weff, cptr, d_out, flag);
}

// Round 4
// 408.075 us; speedup vs baseline: 1.2631x; 1.2631x over previous
//
#include <hip/hip_runtime.h>
#include <stdint.h>

#define GN 2048
#define EN 512
#define BN 16

__device__ __forceinline__ float bf2f(unsigned short u) {
    return __uint_as_float(((unsigned int)u) << 16);
}
__device__ __forceinline__ unsigned short f2bf(float f) {
    unsigned int u = __float_as_uint(f);
    u += 0x7fffu + ((u >> 16) & 1u);   // RNE
    return (unsigned short)(u >> 16);
}
__device__ __forceinline__ float lrelu(float v) { return v > 0.f ? v : 0.01f * v; }

union U16x8 { uint4 v; unsigned short s[8]; };

template<bool ISBF>
__device__ __forceinline__ float ldf(const void* p, size_t i) {
    if (ISBF) return bf2f(((const unsigned short*)p)[i]);
    return ((const float*)p)[i];
}

template<bool ISBF>
__device__ __forceinline__ void ld8(const void* p, size_t off, float* v) {
    if (ISBF) {
        U16x8 u; u.v = *(const uint4*)((const unsigned short*)p + off);
        #pragma unroll
        for (int i = 0; i < 8; i++) v[i] = bf2f(u.s[i]);
    } else {
        const float* q = (const float*)p + off;
        const float4 a = *(const float4*)q;
        const float4 b = *(const float4*)(q + 4);
        v[0]=a.x; v[1]=a.y; v[2]=a.z; v[3]=a.w;
        v[4]=b.x; v[5]=b.y; v[6]=b.z; v[7]=b.w;
    }
}

// ---------------------------------------------------------------------------
// SNIFF: bf16 vs fp32 runtime detection on embMat (~N(0,1)).
// ---------------------------------------------------------------------------
__global__ void sniff_k(const unsigned int* __restrict__ emb, int* __restrict__ flag) {
    const int t = threadIdx.x;
    const unsigned int w = emb[t];
    const int e = (w >> 7) & 0xFF;
    const int ok = (e >= 108 && e <= 134) ? 1 : 0;
    const unsigned long long m = __ballot(ok);
    if (t == 0) flag[0] = (__popcll(m) >= 40) ? 1 : 0;
}

// ---------------------------------------------------------------------------
// SETUP (grid 400):
//  blocks [0,16):    xpackT[t][b] bytes: bit i = (datax[b, 8t+i] != 0)
//  blocks [16,272):  qk — one wave per (W in {Wq,Wk}, f): dots vs emb rows 0,1
//  blocks [272,400): weff partials — block pb covers rows [16pb,16pb+16)
// ---------------------------------------------------------------------------
template<bool ISBF>
__device__ __forceinline__ void setup_body(
    const int* __restrict__ datax, const void* emb, const void* Wq, const void* Wk,
    const void* fc1w, const void* fcCox,
    unsigned char* __restrict__ xpackT, float* __restrict__ qk,
    float* __restrict__ partials)
{
    const int blk = blockIdx.x;
    const int t = threadIdx.x;

    if (blk < 16) {
        const int b = blk;
        unsigned int byte = 0;
        const int base = b * GN + t * 8;
        #pragma unroll
        for (int i = 0; i < 8; i++)
            byte |= (datax[base + i] != 0 ? 1u : 0u) << i;
        xpackT[t * 16 + b] = (unsigned char)byte;
    } else if (blk < 272) {
        const int iw = (blk - 16) * 4 + (t >> 6);   // 0..1023
        const int lane = t & 63;
        const void* W = (iw < 512) ? Wq : Wk;
        const int f = iw & 511;
        float w8[8], e0[8], e1[8];
        ld8<ISBF>(W, (size_t)f * EN + lane * 8, w8);
        ld8<ISBF>(emb, (size_t)lane * 8, e0);
        ld8<ISBF>(emb, (size_t)EN + lane * 8, e1);
        float d0 = 0.f, d1 = 0.f;
        #pragma unroll
        for (int i = 0; i < 8; i++) { d0 += w8[i] * e0[i]; d1 += w8[i] * e1[i]; }
        for (int o = 32; o >= 1; o >>= 1) {
            d0 += __shfl_xor(d0, o);
            d1 += __shfl_xor(d1, o);
        }
        if (lane == 0) {
            const int base = (iw < 512) ? 0 : 1024;
            qk[base + f] = d0;          // dot with emb row 0
            qk[base + 512 + f] = d1;    // dot with emb row 1
        }
    } else {
        const int pb = blk - 272;                    // 0..127
        float acc[8] = {0.f,0.f,0.f,0.f,0.f,0.f,0.f,0.f};
        for (int r = 0; r < 16; r++) {
            const int g = pb * 16 + r;
            const float c = ldf<ISBF>(fcCox, g);
            float w8[8];
            ld8<ISBF>(fc1w, (size_t)g * GN + t * 8, w8);
            #pragma unroll
            for (int i = 0; i < 8; i++) acc[i] += c * w8[i];
        }
        float* q = partials + (size_t)pb * GN + t * 8;
        *(float4*)q       = make_float4(acc[0], acc[1], acc[2], acc[3]);
        *(float4*)(q + 4) = make_float4(acc[4], acc[5], acc[6], acc[7]);
    }
}

__global__ __launch_bounds__(256) void setup_k(
    const int* datax, const void* emb, const void* Wq, const void* Wk,
    const void* fc1w, const void* fcCox,
    unsigned char* xpackT, float* qk, float* partials, const int* flag)
{
    if (flag[0]) setup_body<true>(datax, emb, Wq, Wk, fc1w, fcCox, xpackT, qk, partials);
    else         setup_body<false>(datax, emb, Wq, Wk, fc1w, fcCox, xpackT, qk, partials);
}

// ---------------------------------------------------------------------------
// PRE2 (grid 9): block 0: s00..s11 + bias-dot constant; blocks 1..8: weff reduce
// ---------------------------------------------------------------------------
template<bool ISBF>
__device__ __forceinline__ void pre2_body(
    const float* __restrict__ qk, const void* fc1b, const void* fcCox,
    const float* __restrict__ partials,
    float* __restrict__ sv, float* __restrict__ cptr, float* __restrict__ weff)
{
    const int t = threadIdx.x;
    if (blockIdx.x > 0) {
        const int c = (blockIdx.x - 1) * 256 + t;
        float acc = 0.f;
        for (int r = 0; r < 128; r++)
            acc += partials[(size_t)r * GN + c];
        weff[c] = acc;
        return;
    }
    float a[5] = {0.f, 0.f, 0.f, 0.f, 0.f};
    for (int e = t; e < EN; e += 256) {
        float q0 = qk[e], q1 = qk[EN + e];
        float K0 = qk[2 * EN + e], K1 = qk[3 * EN + e];
        a[0] += q0 * K0; a[1] += q0 * K1; a[2] += q1 * K0; a[3] += q1 * K1;
    }
    for (int gg = t; gg < GN; gg += 256)
        a[4] += ldf<ISBF>(fc1b, gg) * ldf<ISBF>(fcCox, gg);
    for (int o = 32; o >= 1; o >>= 1)
        #pragma unroll
        for (int j = 0; j < 5; j++) a[j] += __shfl_xor(a[j], o);
    __shared__ float red[4][5];
    int wid = t >> 6, lane = t & 63;
    if (lane == 0)
        for (int j = 0; j < 5; j++) red[wid][j] = a[j];
    __syncthreads();
    if (t == 0) {
        for (int j = 0; j < 4; j++)
            sv[j] = red[0][j] + red[1][j] + red[2][j] + red[3][j];
        cptr[0] = red[0][4] + red[1][4] + red[2][4] + red[3][4];
    }
}

__global__ __launch_bounds__(256) void pre2_k(
    const float* qk, const void* fc1b, const void* fcCox, const float* partials,
    float* sv, float* cptr, float* weff, const int* flag)
{
    if (flag[0]) pre2_body<true>(qk, fc1b, fcCox, partials, sv, cptr, weff);
    else         pre2_body<false>(qk, fc1b, fcCox, partials, sv, cptr, weff);
}

// ---------------------------------------------------------------------------
// MAIN fused (grid 2048): one block per g-row. 4-variant select epilogue,
// PLAIN cached stores (measured: no write amplification, vs 1.3-1.8x for nt).
// Store order over batch planes rotated by g&15 to spread concurrent streams.
// ---------------------------------------------------------------------------
template<bool ISBF>
__device__ __forceinline__ void attn_body(
    const void* k1, const void* k2, const void* k3,
    const void* sp, const void* cen, const void* pad,
    const unsigned char* __restrict__ xpackT, const float* __restrict__ sv,
    float* __restrict__ attn2, void* d_out)
{
    const int g = blockIdx.x;
    const int t = threadIdx.x;
    const int h0 = t << 3;
    const size_t roff = (size_t)g * GN + h0;

    const float lr3 = lrelu(ldf<ISBF>(k3, 0));

    float a1[8], a2[8], vsp[8], vcn[8], vpd[8];
    ld8<ISBF>(k1, roff, a1);
    ld8<ISBF>(k2, roff, a2);
    ld8<ISBF>(sp, roff, vsp);
    ld8<ISBF>(cen, roff, vcn);
    ld8<ISBF>(pad, roff, vpd);

    float bias8[8];
    float lmax = -3.4e38f;
    #pragma unroll
    for (int i = 0; i < 8; i++) {
        float b = lrelu(a1[i]) * vsp[i] + lrelu(a2[i]) * vcn[i] + lr3 * vpd[i];
        bias8[i] = b;
        lmax = fmaxf(lmax, b);
    }
    for (int o = 32; o >= 1; o >>= 1) lmax = fmaxf(lmax, __shfl_xor(lmax, o));

    __shared__ float smax[4];
    __shared__ float redT[4];
    __shared__ float red[4][BN];
    const int wid = t >> 6, lane = t & 63;
    if (lane == 0) smax[wid] = lmax;
    __syncthreads();
    const float Mg = fmaxf(fmaxf(smax[0], smax[1]), fmaxf(smax[2], smax[3]));

    float E8[8];
    float Tl = 0.f;
    #pragma unroll
    for (int i = 0; i < 8; i++) { E8[i] = __expf(bias8[i] - Mg); Tl += E8[i]; }

    // packed membership bits: byte b of this uint4 = bits for batch b, h0..h0+7
    const uint4 pk = *(const uint4*)(xpackT + (size_t)t * 16);
    const unsigned char* pb = (const unsigned char*)&pk;

    float s1l[BN];
    #pragma unroll
    for (int b = 0; b < BN; b++) {
        const unsigned int mk = pb[b];
        float acc1 = 0.f;
        #pragma unroll
        for (int i = 0; i < 8; i++)
            acc1 += ((mk >> i) & 1u) ? E8[i] : 0.f;
        s1l[b] = acc1;
    }
    for (int o = 32; o >= 1; o >>= 1) {
        Tl += __shfl_xor(Tl, o);
        #pragma unroll
        for (int b = 0; b < BN; b++) s1l[b] += __shfl_xor(s1l[b], o);
    }
    if (lane == 0) {
        redT[wid] = Tl;
        #pragma unroll
        for (int b = 0; b < BN; b++) red[wid][b] = s1l[b];
    }
    __syncthreads();

    const float s00 = sv[0], s01 = sv[1], s10 = sv[2], s11 = sv[3];
    // membership bits of column g for all 16 batches:
    const uint4 gk = *(const uint4*)(xpackT + (size_t)(g >> 3) * 16);
    const unsigned char* gb = (const unsigned char*)&gk;
    const int gbit = g & 7;

    // --- attnv sigmoid chain: one batch per lane, t < 16 only ---
    if (t < BN) {
        const int b = t;
        const float Tg = redT[0] + redT[1] + redT[2] + redT[3];
        const float S1 = fmaxf(red[0][b] + red[1][b] + red[2][b] + red[3][b], 1e-30f);
        const float S0 = fmaxf(Tg - S1, 1e-30f);
        const bool on = ((gb[b] >> gbit) & 1u) != 0u;
        const float sa0 = on ? s10 : s00;
        const float sa1 = on ? s11 : s01;
        const float d = (sa0 + __logf(S0)) - (sa1 + __logf(S1));
        const float attnv = 1.f / (1.f + __expf(d));
        attn2[b * GN + g] = (on ? 1.f : 0.f) + attnv;
    }

    // --- 4-variant precompute: ov[i] = bias8[i] + s[on][bit] exactly ---
    const int brot = g & 15;
    if (ISBF) {
        U16x8 p00, p01, p10, p11;
        #pragma unroll
        for (int i = 0; i < 8; i++) {
            p00.s[i] = f2bf(bias8[i] + s00);
            p01.s[i] = f2bf(bias8[i] + s01);
            p10.s[i] = f2bf(bias8[i] + s10);
            p11.s[i] = f2bf(bias8[i] + s11);
        }
        unsigned short* outp = (unsigned short*)d_out + BN + (size_t)g * GN + h0;
        #pragma unroll
        for (int bb = 0; bb < BN; bb++) {
            const int b = (bb + brot) & 15;
            const unsigned int mk = pb[b];
            const bool on = ((gb[b] >> gbit) & 1u) != 0u;
            U16x8 lo, hi;
            if (on) { lo = p10; hi = p11; } else { lo = p00; hi = p01; }
            U16x8 o;
            #pragma unroll
            for (int i = 0; i < 8; i++)
                o.s[i] = ((mk >> i) & 1u) ? hi.s[i] : lo.s[i];
            *(uint4*)(outp + (size_t)b * GN * GN) = o.v;
        }
    } else {
        float v00[8], v01[8], v10[8], v11[8];
        #pragma unroll
        for (int i = 0; i < 8; i++) {
            v00[i] = bias8[i] + s00;
            v01[i] = bias8[i] + s01;
            v10[i] = bias8[i] + s10;
            v11[i] = bias8[i] + s11;
        }
        float* outp = (float*)d_out + BN + (size_t)g * GN + h0;
        #pragma unroll
        for (int bb = 0; bb < BN; bb++) {
            const int b = (bb + brot) & 15;
            const unsigned int mk = pb[b];
            const bool on = ((gb[b] >> gbit) & 1u) != 0u;
            float ov[8];
            #pragma unroll
            for (int i = 0; i < 8; i++) {
                const float lo = on ? v10[i] : v00[i];
                const float hi = on ? v11[i] : v01[i];
                ov[i] = ((mk >> i) & 1u) ? hi : lo;
            }
            float* q = outp + (size_t)b * GN * GN;
            *(float4*)q       = make_float4(ov[0], ov[1], ov[2], ov[3]);
            *(float4*)(q + 4) = make_float4(ov[4], ov[5], ov[6], ov[7]);
        }
    }
}

__global__ __launch_bounds__(256) void attn_k(
    const void* k1, const void* k2, const void* k3,
    const void* sp, const void* cen, const void* pad,
    const unsigned char* xpackT, const float* sv, float* attn2,
    void* d_out, const int* flag)
{
    if (flag[0]) attn_body<true>(k1, k2, k3, sp, cen, pad, xpackT, sv, attn2, d_out);
    else         attn_body<false>(k1, k2, k3, sp, cen, pad, xpackT, sv, attn2, d_out);
}

// ---------------------------------------------------------------------------
// FIN: out[b] = c + sum_g attn2[b,g] * w_eff[g]
// ---------------------------------------------------------------------------
template<bool ISBF>
__device__ __forceinline__ void final_body(
    const float* __restrict__ attn2, const float* __restrict__ weff,
    const float* __restrict__ cptr, void* d_out)
{
    const int b = blockIdx.x, t = threadIdx.x;
    const int h0 = t << 3;
    const float4 a0 = *(const float4*)(attn2 + b * GN + h0);
    const float4 a1 = *(const float4*)(attn2 + b * GN + h0 + 4);
    const float4 w0 = *(const float4*)(weff + h0);
    const float4 w1 = *(const float4*)(weff + h0 + 4);
    float acc = a0.x * w0.x + a0.y * w0.y + a0.z * w0.z + a0.w * w0.w
              + a1.x * w1.x + a1.y * w1.y + a1.z * w1.z + a1.w * w1.w;
    for (int o = 32; o >= 1; o >>= 1) acc += __shfl_xor(acc, o);
    __shared__ float red[4];
    const int wid = t >> 6, lane = t & 63;
    if (lane == 0) red[wid] = acc;
    __syncthreads();
    if (t == 0) {
        const float val = cptr[0] + red[0] + red[1] + red[2] + red[3];
        if (ISBF) ((unsigned short*)d_out)[b] = f2bf(val);
        else      ((float*)d_out)[b] = val;
    }
}

__global__ __launch_bounds__(256) void final_k(
    const float* attn2, const float* weff, const float* cptr,
    void* d_out, const int* flag)
{
    if (flag[0]) final_body<true>(attn2, weff, cptr, d_out);
    else         final_body<false>(attn2, weff, cptr, d_out);
}

extern "C" void kernel_launch(void* const* d_in, const int* in_sizes, int n_in,
                              void* d_out, int out_size, void* d_ws, size_t ws_size,
                              hipStream_t stream) {
    const int*  datax = (const int*)d_in[0];
    const void* emb   = d_in[1];
    const void* Wq    = d_in[2];
    const void* Wk    = d_in[3];
    const void* k1    = d_in[4];
    const void* k2    = d_in[5];
    const void* k3    = d_in[6];
    const void* sp    = d_in[7];
    const void* cen   = d_in[8];
    const void* pad   = d_in[9];
    const void* fc1w  = d_in[10];
    const void* fc1b  = d_in[11];
    const void* fcCox = d_in[12];

    float* ws       = (float*)d_ws;
    float* qk       = ws;                   // 2048 floats
    float* sv       = ws + 2048;            // 4
    float* cptr     = ws + 2052;            // 1
    float* weff     = ws + 2056;            // 2048
    float* attn2    = ws + 4104;            // 32768
    float* partials = ws + 36872;           // 128*2048 = 262144
    unsigned char* xpackT = (unsigned char*)(ws + 299016); // 4096 B
    int*   flag     = (int*)(ws + 300040);  // 1 int

    sniff_k<<<1, 64, 0, stream>>>((const unsigned int*)emb, flag);
    setup_k<<<400, 256, 0, stream>>>(datax, emb, Wq, Wk, fc1w, fcCox,
                                     xpackT, qk, partials, flag);
    pre2_k<<<9, 256, 0, stream>>>(qk, fc1b, fcCox, partials, sv, cptr, weff, flag);
    attn_k<<<GN, 256, 0, stream>>>(k1, k2, k3, sp, cen, pad, xpackT, sv, attn2, d_out, flag);
    final_k<<<BN, 256, 0, stream>>>(attn2, weff, cptr, d_out, flag);
}

// Round 5
// 397.480 us; speedup vs baseline: 1.2967x; 1.0267x over previous
//
#include <hip/hip_runtime.h>
#include <stdint.h>

#define GN 2048
#define EN 512
#define BN 16

__device__ __forceinline__ float bf2f(unsigned short u) {
    return __uint_as_float(((unsigned int)u) << 16);
}
__device__ __forceinline__ unsigned short f2bf(float f) {
    unsigned int u = __float_as_uint(f);
    u += 0x7fffu + ((u >> 16) & 1u);   // RNE
    return (unsigned short)(u >> 16);
}
__device__ __forceinline__ float lrelu(float v) { return v > 0.f ? v : 0.01f * v; }

union U16x8 { uint4 v; unsigned short s[8]; };

// register-only byte extraction from a uint4 (no dynamic indexing -> no scratch)
__device__ __forceinline__ unsigned int byte_of(const uint4& v, int b) {
    const unsigned long long lo = ((unsigned long long)v.y << 32) | v.x;
    const unsigned long long hi = ((unsigned long long)v.w << 32) | v.z;
    const unsigned long long sel = (b & 8) ? hi : lo;
    return (unsigned int)(sel >> ((b & 7) * 8)) & 0xFFu;
}

template<bool ISBF>
__device__ __forceinline__ float ldf(const void* p, size_t i) {
    if (ISBF) return bf2f(((const unsigned short*)p)[i]);
    return ((const float*)p)[i];
}

template<bool ISBF>
__device__ __forceinline__ void ld8(const void* p, size_t off, float* v) {
    if (ISBF) {
        U16x8 u; u.v = *(const uint4*)((const unsigned short*)p + off);
        #pragma unroll
        for (int i = 0; i < 8; i++) v[i] = bf2f(u.s[i]);
    } else {
        const float* q = (const float*)p + off;
        const float4 a = *(const float4*)q;
        const float4 b = *(const float4*)(q + 4);
        v[0]=a.x; v[1]=a.y; v[2]=a.z; v[3]=a.w;
        v[4]=b.x; v[5]=b.y; v[6]=b.z; v[7]=b.w;
    }
}

// ---------------------------------------------------------------------------
// SNIFF: bf16 vs fp32 runtime detection on embMat (~N(0,1)).
// ---------------------------------------------------------------------------
__global__ void sniff_k(const unsigned int* __restrict__ emb, int* __restrict__ flag) {
    const int t = threadIdx.x;
    const unsigned int w = emb[t];
    const int e = (w >> 7) & 0xFF;
    const int ok = (e >= 108 && e <= 134) ? 1 : 0;
    const unsigned long long m = __ballot(ok);
    if (t == 0) flag[0] = (__popcll(m) >= 40) ? 1 : 0;
}

// ---------------------------------------------------------------------------
// SETUP (grid 400):
//  blocks [0,16):    xpackT[t][b] bytes: bit i = (datax[b, 8t+i] != 0)
//  blocks [16,272):  qk — one wave per (W in {Wq,Wk}, f): dots vs emb rows 0,1
//  blocks [272,400): weff partials — block pb covers rows [16pb,16pb+16)
// ---------------------------------------------------------------------------
template<bool ISBF>
__device__ __forceinline__ void setup_body(
    const int* __restrict__ datax, const void* emb, const void* Wq, const void* Wk,
    const void* fc1w, const void* fcCox,
    unsigned char* __restrict__ xpackT, float* __restrict__ qk,
    float* __restrict__ partials)
{
    const int blk = blockIdx.x;
    const int t = threadIdx.x;

    if (blk < 16) {
        const int b = blk;
        unsigned int byte = 0;
        const int base = b * GN + t * 8;
        #pragma unroll
        for (int i = 0; i < 8; i++)
            byte |= (datax[base + i] != 0 ? 1u : 0u) << i;
        xpackT[t * 16 + b] = (unsigned char)byte;
    } else if (blk < 272) {
        const int iw = (blk - 16) * 4 + (t >> 6);   // 0..1023
        const int lane = t & 63;
        const void* W = (iw < 512) ? Wq : Wk;
        const int f = iw & 511;
        float w8[8], e0[8], e1[8];
        ld8<ISBF>(W, (size_t)f * EN + lane * 8, w8);
        ld8<ISBF>(emb, (size_t)lane * 8, e0);
        ld8<ISBF>(emb, (size_t)EN + lane * 8, e1);
        float d0 = 0.f, d1 = 0.f;
        #pragma unroll
        for (int i = 0; i < 8; i++) { d0 += w8[i] * e0[i]; d1 += w8[i] * e1[i]; }
        for (int o = 32; o >= 1; o >>= 1) {
            d0 += __shfl_xor(d0, o);
            d1 += __shfl_xor(d1, o);
        }
        if (lane == 0) {
            const int base = (iw < 512) ? 0 : 1024;
            qk[base + f] = d0;          // dot with emb row 0
            qk[base + 512 + f] = d1;    // dot with emb row 1
        }
    } else {
        const int pb = blk - 272;                    // 0..127
        float acc[8] = {0.f,0.f,0.f,0.f,0.f,0.f,0.f,0.f};
        for (int r = 0; r < 16; r++) {
            const int g = pb * 16 + r;
            const float c = ldf<ISBF>(fcCox, g);
            float w8[8];
            ld8<ISBF>(fc1w, (size_t)g * GN + t * 8, w8);
            #pragma unroll
            for (int i = 0; i < 8; i++) acc[i] += c * w8[i];
        }
        float* q = partials + (size_t)pb * GN + t * 8;
        *(float4*)q       = make_float4(acc[0], acc[1], acc[2], acc[3]);
        *(float4*)(q + 4) = make_float4(acc[4], acc[5], acc[6], acc[7]);
    }
}

__global__ __launch_bounds__(256) void setup_k(
    const int* datax, const void* emb, const void* Wq, const void* Wk,
    const void* fc1w, const void* fcCox,
    unsigned char* xpackT, float* qk, float* partials, const int* flag)
{
    if (flag[0]) setup_body<true>(datax, emb, Wq, Wk, fc1w, fcCox, xpackT, qk, partials);
    else         setup_body<false>(datax, emb, Wq, Wk, fc1w, fcCox, xpackT, qk, partials);
}

// ---------------------------------------------------------------------------
// PRE2 (grid 9): block 0: s00..s11 + bias-dot constant; blocks 1..8: weff reduce
// ---------------------------------------------------------------------------
template<bool ISBF>
__device__ __forceinline__ void pre2_body(
    const float* __restrict__ qk, const void* fc1b, const void* fcCox,
    const float* __restrict__ partials,
    float* __restrict__ sv, float* __restrict__ cptr, float* __restrict__ weff)
{
    const int t = threadIdx.x;
    if (blockIdx.x > 0) {
        const int c = (blockIdx.x - 1) * 256 + t;
        float acc = 0.f;
        for (int r = 0; r < 128; r++)
            acc += partials[(size_t)r * GN + c];
        weff[c] = acc;
        return;
    }
    float a[5] = {0.f, 0.f, 0.f, 0.f, 0.f};
    for (int e = t; e < EN; e += 256) {
        float q0 = qk[e], q1 = qk[EN + e];
        float K0 = qk[2 * EN + e], K1 = qk[3 * EN + e];
        a[0] += q0 * K0; a[1] += q0 * K1; a[2] += q1 * K0; a[3] += q1 * K1;
    }
    for (int gg = t; gg < GN; gg += 256)
        a[4] += ldf<ISBF>(fc1b, gg) * ldf<ISBF>(fcCox, gg);
    for (int o = 32; o >= 1; o >>= 1)
        #pragma unroll
        for (int j = 0; j < 5; j++) a[j] += __shfl_xor(a[j], o);
    __shared__ float red[4][5];
    int wid = t >> 6, lane = t & 63;
    if (lane == 0)
        for (int j = 0; j < 5; j++) red[wid][j] = a[j];
    __syncthreads();
    if (t == 0) {
        for (int j = 0; j < 4; j++)
            sv[j] = red[0][j] + red[1][j] + red[2][j] + red[3][j];
        cptr[0] = red[0][4] + red[1][4] + red[2][4] + red[3][4];
    }
}

__global__ __launch_bounds__(256) void pre2_k(
    const float* qk, const void* fc1b, const void* fcCox, const float* partials,
    float* sv, float* cptr, float* weff, const int* flag)
{
    if (flag[0]) pre2_body<true>(qk, fc1b, fcCox, partials, sv, cptr, weff);
    else         pre2_body<false>(qk, fc1b, fcCox, partials, sv, cptr, weff);
}

// ---------------------------------------------------------------------------
// MAIN fused (grid 512): 4 rows per block. XCD-bijective swizzle gives each
// XCD a contiguous 256-row band; per plane each block stores a 32 KB
// contiguous burst (4 adjacent 8 KB rows) -> 4x fewer, 4x longer write
// streams than the 1-row version. Plain cached stores (no amplification).
// ---------------------------------------------------------------------------
template<bool ISBF>
__device__ __forceinline__ void attn_body(
    const void* k1, const void* k2, const void* k3,
    const void* sp, const void* cen, const void* pad,
    const unsigned char* __restrict__ xpackT, const float* __restrict__ sv,
    float* __restrict__ attn2, void* d_out)
{
    const int id  = blockIdx.x;                  // 0..511
    const int idp = ((id & 7) << 6) | (id >> 3); // XCD-contiguous band (bijective)
    const int G0  = idp << 2;                    // base row; rows G0..G0+3
    const int t   = threadIdx.x;
    const int h0  = t << 3;

    const float lr3 = lrelu(ldf<ISBF>(k3, 0));

    // ---- bias for 4 rows (20 wide loads, deep MLP) ----
    float bias[4][8];
    float lmax[4];
    #pragma unroll
    for (int r = 0; r < 4; r++) {
        const size_t roff = (size_t)(G0 + r) * GN + h0;
        float a1[8], a2[8], vsp[8], vcn[8], vpd[8];
        ld8<ISBF>(k1, roff, a1);
        ld8<ISBF>(k2, roff, a2);
        ld8<ISBF>(sp, roff, vsp);
        ld8<ISBF>(cen, roff, vcn);
        ld8<ISBF>(pad, roff, vpd);
        float lm = -3.4e38f;
        #pragma unroll
        for (int i = 0; i < 8; i++) {
            float b = lrelu(a1[i]) * vsp[i] + lrelu(a2[i]) * vcn[i] + lr3 * vpd[i];
            bias[r][i] = b;
            lm = fmaxf(lm, b);
        }
        lmax[r] = lm;
    }
    #pragma unroll
    for (int o = 32; o >= 1; o >>= 1)
        #pragma unroll
        for (int r = 0; r < 4; r++) lmax[r] = fmaxf(lmax[r], __shfl_xor(lmax[r], o));

    __shared__ float smax[4][4];      // [wid][r]
    __shared__ float redT[4][4];      // [wid][r]
    __shared__ float red[4][4][BN];   // [wid][r][b]
    const int wid = t >> 6, lane = t & 63;
    if (lane == 0)
        #pragma unroll
        for (int r = 0; r < 4; r++) smax[wid][r] = lmax[r];
    __syncthreads();
    float Mg[4];
    #pragma unroll
    for (int r = 0; r < 4; r++)
        Mg[r] = fmaxf(fmaxf(smax[0][r], smax[1][r]), fmaxf(smax[2][r], smax[3][r]));

    // packed membership bits: byte b = bits for batch b, cols h0..h0+7
    const uint4 pk = *(const uint4*)(xpackT + (size_t)t * 16);

    // ---- exp + per-batch masked sums, 4 rows ----
    float Tl[4], s1l[4][BN];
    #pragma unroll
    for (int r = 0; r < 4; r++) {
        float E8[8]; float T = 0.f;
        #pragma unroll
        for (int i = 0; i < 8; i++) { E8[i] = __expf(bias[r][i] - Mg[r]); T += E8[i]; }
        Tl[r] = T;
        #pragma unroll
        for (int b = 0; b < BN; b++) {
            const unsigned int mk = byte_of(pk, b);
            float acc = 0.f;
            #pragma unroll
            for (int i = 0; i < 8; i++) acc += ((mk >> i) & 1u) ? E8[i] : 0.f;
            s1l[r][b] = acc;
        }
    }
    #pragma unroll
    for (int o = 32; o >= 1; o >>= 1) {
        #pragma unroll
        for (int r = 0; r < 4; r++) {
            Tl[r] += __shfl_xor(Tl[r], o);
            #pragma unroll
            for (int b = 0; b < BN; b++) s1l[r][b] += __shfl_xor(s1l[r][b], o);
        }
    }
    if (lane == 0) {
        #pragma unroll
        for (int r = 0; r < 4; r++) {
            redT[wid][r] = Tl[r];
            #pragma unroll
            for (int b = 0; b < BN; b++) red[wid][r][b] = s1l[r][b];
        }
    }
    __syncthreads();

    const float s00 = sv[0], s01 = sv[1], s10 = sv[2], s11 = sv[3];
    // membership bits of rows G0..G0+3 for all batches (one byte-group: G0%8 in {0,4})
    const uint4 gk = *(const uint4*)(xpackT + (size_t)(G0 >> 3) * 16);
    const int gsh = G0 & 7;   // row r uses bit (gsh + r)

    // ---- attnv sigmoid chain: 64 lanes cover (b, r) pairs ----
    if (t < 64) {
        const int b = t & 15, r = t >> 4;
        const float Tg = redT[0][r] + redT[1][r] + redT[2][r] + redT[3][r];
        const float S1 = fmaxf(red[0][r][b] + red[1][r][b] + red[2][r][b] + red[3][r][b], 1e-30f);
        const float S0 = fmaxf(Tg - S1, 1e-30f);
        const bool on = ((byte_of(gk, b) >> (gsh + r)) & 1u) != 0u;
        const float sa0 = on ? s10 : s00;
        const float sa1 = on ? s11 : s01;
        const float d = (sa0 + __logf(S0)) - (sa1 + __logf(S1));
        const float attnv = 1.f / (1.f + __expf(d));
        attn2[b * GN + (G0 + r)] = (on ? 1.f : 0.f) + attnv;
    }

    // ---- stores: per plane, a 32 KB contiguous burst (rows G0..G0+3) ----
    const int prot = idp & 15;  // rotate start plane across neighboring blocks
    if (ISBF) {
        U16x8 p00[4], p01[4], p10[4], p11[4];
        #pragma unroll
        for (int r = 0; r < 4; r++)
            #pragma unroll
            for (int i = 0; i < 8; i++) {
                p00[r].s[i] = f2bf(bias[r][i] + s00);
                p01[r].s[i] = f2bf(bias[r][i] + s01);
                p10[r].s[i] = f2bf(bias[r][i] + s10);
                p11[r].s[i] = f2bf(bias[r][i] + s11);
            }
        unsigned short* outp = (unsigned short*)d_out + BN + h0;
        #pragma unroll
        for (int bb = 0; bb < BN; bb++) {
            const int b = (bb + prot) & 15;
            const unsigned int mk = byte_of(pk, b);
            const unsigned int gbyte = byte_of(gk, b);
            unsigned short* bp = outp + (size_t)b * GN * GN;
            #pragma unroll
            for (int r = 0; r < 4; r++) {
                const bool on = ((gbyte >> (gsh + r)) & 1u) != 0u;
                U16x8 lo, hi;
                if (on) { lo = p10[r]; hi = p11[r]; } else { lo = p00[r]; hi = p01[r]; }
                U16x8 o;
                #pragma unroll
                for (int i = 0; i < 8; i++)
                    o.s[i] = ((mk >> i) & 1u) ? hi.s[i] : lo.s[i];
                *(uint4*)(bp + (size_t)(G0 + r) * GN) = o.v;
            }
        }
    } else {
        float* outp = (float*)d_out + BN + h0;
        #pragma unroll
        for (int bb = 0; bb < BN; bb++) {
            const int b = (bb + prot) & 15;
            const unsigned int mk = byte_of(pk, b);
            const unsigned int gbyte = byte_of(gk, b);
            float* bp = outp + (size_t)b * GN * GN;
            #pragma unroll
            for (int r = 0; r < 4; r++) {
                const bool on = ((gbyte >> (gsh + r)) & 1u) != 0u;
                const float c0 = on ? s10 : s00;
                const float c1 = on ? s11 : s01;
                float ov[8];
                #pragma unroll
                for (int i = 0; i < 8; i++)
                    ov[i] = bias[r][i] + (((mk >> i) & 1u) ? c1 : c0);
                float* q = bp + (size_t)(G0 + r) * GN;
                *(float4*)q       = make_float4(ov[0], ov[1], ov[2], ov[3]);
                *(float4*)(q + 4) = make_float4(ov[4], ov[5], ov[6], ov[7]);
            }
        }
    }
}

__global__ __launch_bounds__(256) void attn_k(
    const void* k1, const void* k2, const void* k3,
    const void* sp, const void* cen, const void* pad,
    const unsigned char* xpackT, const float* sv, float* attn2,
    void* d_out, const int* flag)
{
    if (flag[0]) attn_body<true>(k1, k2, k3, sp, cen, pad, xpackT, sv, attn2, d_out);
    else         attn_body<false>(k1, k2, k3, sp, cen, pad, xpackT, sv, attn2, d_out);
}

// ---------------------------------------------------------------------------
// FIN: out[b] = c + sum_g attn2[b,g] * w_eff[g]
// ---------------------------------------------------------------------------
template<bool ISBF>
__device__ __forceinline__ void final_body(
    const float* __restrict__ attn2, const float* __restrict__ weff,
    const float* __restrict__ cptr, void* d_out)
{
    const int b = blockIdx.x, t = threadIdx.x;
    const int h0 = t << 3;
    const float4 a0 = *(const float4*)(attn2 + b * GN + h0);
    const float4 a1 = *(const float4*)(attn2 + b * GN + h0 + 4);
    const float4 w0 = *(const float4*)(weff + h0);
    const float4 w1 = *(const float4*)(weff + h0 + 4);
    float acc = a0.x * w0.x + a0.y * w0.y + a0.z * w0.z + a0.w * w0.w
              + a1.x * w1.x + a1.y * w1.y + a1.z * w1.z + a1.w * w1.w;
    for (int o = 32; o >= 1; o >>= 1) acc += __shfl_xor(acc, o);
    __shared__ float red[4];
    const int wid = t >> 6, lane = t & 63;
    if (lane == 0) red[wid] = acc;
    __syncthreads();
    if (t == 0) {
        const float val = cptr[0] + red[0] + red[1] + red[2] + red[3];
        if (ISBF) ((unsigned short*)d_out)[b] = f2bf(val);
        else      ((float*)d_out)[b] = val;
    }
}

__global__ __launch_bounds__(256) void final_k(
    const float* attn2, const float* weff, const float* cptr,
    void* d_out, const int* flag)
{
    if (flag[0]) final_body<true>(attn2, weff, cptr, d_out);
    else         final_body<false>(attn2, weff, cptr, d_out);
}

extern "C" void kernel_launch(void* const* d_in, const int* in_sizes, int n_in,
                              void* d_out, int out_size, void* d_ws, size_t ws_size,
                              hipStream_t stream) {
    const int*  datax = (const int*)d_in[0];
    const void* emb   = d_in[1];
    const void* Wq    = d_in[2];
    const void* Wk    = d_in[3];
    const void* k1    = d_in[4];
    const void* k2    = d_in[5];
    const void* k3    = d_in[6];
    const void* sp    = d_in[7];
    const void* cen   = d_in[8];
    const void* pad   = d_in[9];
    const void* fc1w  = d_in[10];
    const void* fc1b  = d_in[11];
    const void* fcCox = d_in[12];

    float* ws       = (float*)d_ws;
    float* qk       = ws;                   // 2048 floats
    float* sv       = ws + 2048;            // 4
    float* cptr     = ws + 2052;            // 1
    float* weff     = ws + 2056;            // 2048
    float* attn2    = ws + 4104;            // 32768
    float* partials = ws + 36872;           // 128*2048 = 262144
    unsigned char* xpackT = (unsigned char*)(ws + 299016); // 4096 B
    int*   flag     = (int*)(ws + 300040);  // 1 int

    sniff_k<<<1, 64, 0, stream>>>((const unsigned int*)emb, flag);
    setup_k<<<400, 256, 0, stream>>>(datax, emb, Wq, Wk, fc1w, fcCox,
                                     xpackT, qk, partials, flag);
    pre2_k<<<9, 256, 0, stream>>>(qk, fc1b, fcCox, partials, sv, cptr, weff, flag);
    attn_k<<<512, 256, 0, stream>>>(k1, k2, k3, sp, cen, pad, xpackT, sv, attn2, d_out, flag);
    final_k<<<BN, 256, 0, stream>>>(attn2, weff, cptr, d_out, flag);
}